// Round 16
// baseline (122.689 us; speedup 1.0000x reference)
//
#include <hip/hip_runtime.h>
#include <hip/hip_bf16.h>
#include <math.h>

#define CDIM 512
#define NROW 8192
#define BM 256
#define BN 256
#define BK 32
#define NT 16              // K tiles: 512/32
#define NCB 32             // column blocks (8192/256)
#define BUFSZ 32768        // A 16 KB + B 16 KB per K-tile buffer
#define TEMP_INV 10.0f

typedef unsigned short u16;
typedef u16  u16x8 __attribute__((ext_vector_type(8)));
typedef __bf16 bf16x8 __attribute__((ext_vector_type(8)));
typedef float  f32x4 __attribute__((ext_vector_type(4)));

static __device__ __forceinline__ float bf2f(u16 u) {
    return __uint_as_float(((unsigned)u) << 16);
}
static __device__ __forceinline__ u16 f2bf(float f) {
    unsigned u = __float_as_uint(f);
    return (u16)((u + 0x7FFFu + ((u >> 16) & 1u)) >> 16);  // RNE
}

static __device__ __forceinline__ void gload_lds16(const u16* g, char* l) {
    __builtin_amdgcn_global_load_lds(
        (const __attribute__((address_space(1))) void*)g,
        (__attribute__((address_space(3))) void*)l, 16, 0, 0);
}

// ---------------------------------------------------------------------------
// Kernel 1: row-normalize (fp32 math) -> bf16 (RNE). One wave per row.
// ---------------------------------------------------------------------------
__global__ __launch_bounds__(256) void norm_split_kernel(
    const float* __restrict__ x, const float* __restrict__ q,
    u16* __restrict__ xh, u16* __restrict__ qh, int n)
{
    int wave = blockIdx.x * 4 + (threadIdx.x >> 6);
    int lane = threadIdx.x & 63;
    const float* src; u16* dh; int row;
    if (wave < n) { src = x; dh = xh; row = wave; }
    else          { src = q; dh = qh; row = wave - n; }

    const float4* p = reinterpret_cast<const float4*>(src + (size_t)row * CDIM);
    float4 a = p[lane * 2];
    float4 b = p[lane * 2 + 1];
    float v[8] = {a.x, a.y, a.z, a.w, b.x, b.y, b.z, b.w};
    float ss = 0.f;
#pragma unroll
    for (int j = 0; j < 8; ++j) ss += v[j] * v[j];
#pragma unroll
    for (int off = 32; off; off >>= 1) ss += __shfl_xor(ss, off);
    float scale = 1.0f / fmaxf(sqrtf(ss), 1e-12f);

    u16 h[8] __attribute__((aligned(16)));
#pragma unroll
    for (int j = 0; j < 8; ++j) h[j] = f2bf(v[j] * scale);
    *(u16x8*)&dh[(size_t)row * CDIM + lane * 8] = *(u16x8*)h;
}

// ---------------------------------------------------------------------------
// Kernel 2 (R9 restore — measured best: sim 106 us, MfmaUtil 27%, FETCH 37MB,
// conflicts 68k, absmax 0.0):
// 256x256-tile bf16 GEMM (K=512), triple-buffered BK=32, one barrier per
// K-tile. 1024 threads = 16 waves (4 wm x 4 wn), wave tile 64x64.
// Conflict-free chunk swizzle (R5-verified): physical_chunk =
// logical_chunk ^ ((row>>1)&3), applied on BOTH sides (stage pre-swizzles
// the per-lane GLOBAL source; LDS dest linear; frag reads XOR the same
// involution). XCD-resident blocking (R6/R9-verified): xcd = orig&7 owns
// all 32 rb x 4 cb, rb-outer -> co-resident L2 footprint/XCD = 3MB.
// Fused epilogue: per-row (max, sum-exp, argmax) partials + in-tile diag,
// packed float4 -> part[row][cb].
// Post-R10..R14 note: 2-block overlap (R10), 8-phase (R11), B-from-L2 (R12),
// and loop rotation (R13 race / R14 spill) were all counter-falsified;
// this schedule is the empirical fixed point of the design family.
// ---------------------------------------------------------------------------
__global__ __launch_bounds__(1024, 4) void sim_main_kernel(
    const u16* __restrict__ xh, const u16* __restrict__ qh,
    float4* __restrict__ part)
{
    extern __shared__ __align__(16) char smem[];   // 3 * 32768 = 96 KB
    const int t = threadIdx.x, lane = t & 63, wid = t >> 6;
    const int wm = wid >> 2, wn = wid & 3;

    // XCD-resident blocking: orig&7 = XCD (hw round-robin), rb outer, cb inner
    const int orig = blockIdx.x;
    const int xcd = orig & 7, s = orig >> 3;       // s in [0,128)
    const int rb = s >> 2;                          // 0..31
    const int cb = xcd * 4 + (s & 3);               // 0..31
    const int row0 = rb * BM, col0 = cb * BN;

    // staging sources (per-lane): thread t fills LDS row (t>>2), physical
    // chunk (t&3); global chunk = (t&3) ^ ((row>>1)&3) = (t&3) ^ ((t>>3)&3)
    const int schunk = (t & 3) ^ ((t >> 3) & 3);
    const u16* sa = xh + (size_t)(row0 + (t >> 2)) * CDIM + schunk * 8;
    const u16* sb = qh + (size_t)(col0 + (t >> 2)) * CDIM + schunk * 8;
    const unsigned dstw = (unsigned)wid * 1024u;   // wave-uniform dest

    auto stage = [&](int kt) {
        char* b = smem + (kt % 3) * BUFSZ;
        const int ko = kt * BK;
        gload_lds16(sa + ko, b + dstw);             // A: rows 0..255 x 32k
        gload_lds16(sb + ko, b + 16384 + dstw);     // B: rows 0..255 x 32k
    };

    // frag read offsets (row stride 64 B); physical chunk = slot ^ ((row>>1)&3)
    const unsigned kxc = ((unsigned)((lane >> 4) ^ ((lane >> 1) & 3))) * 16u;
    const unsigned aro = ((unsigned)(wm * 64 + (lane & 15))) * 64u + kxc;
    const unsigned bro = 16384u + ((unsigned)(wn * 64 + (lane & 15))) * 64u + kxc;

    f32x4 acc[4][4];
#pragma unroll
    for (int i = 0; i < 4; ++i)
#pragma unroll
        for (int j = 0; j < 4; ++j) acc[i][j] = (f32x4){0.f, 0.f, 0.f, 0.f};

    // prologue: lead-2
    stage(0); stage(1);
    asm volatile("s_waitcnt vmcnt(2)" ::: "memory");   // stage(0) landed
    __builtin_amdgcn_s_barrier();
    asm volatile("" ::: "memory");

    for (int kt = 0; kt < NT; ++kt) {
        const char* buf = smem + (kt % 3) * BUFSZ;
        // issue next-next stage FIRST (loads fly during reads+MFMA)
        if (kt < NT - 2) stage(kt + 2);
        bf16x8 afr[4], bfr[4];
#pragma unroll
        for (int mf = 0; mf < 4; ++mf) afr[mf] = *(const bf16x8*)(buf + aro + mf * 1024u);
#pragma unroll
        for (int nf = 0; nf < 4; ++nf) bfr[nf] = *(const bf16x8*)(buf + bro + nf * 1024u);

        __builtin_amdgcn_s_setprio(1);
#pragma unroll
        for (int mf = 0; mf < 4; ++mf)
#pragma unroll
            for (int nf = 0; nf < 4; ++nf)
                acc[mf][nf] = __builtin_amdgcn_mfma_f32_16x16x32_bf16(
                    afr[mf], bfr[nf], acc[mf][nf], 0, 0, 0);
        __builtin_amdgcn_s_setprio(0);

        if (kt < NT - 2)       { asm volatile("s_waitcnt vmcnt(2)" ::: "memory"); }
        else if (kt == NT - 2) { asm volatile("s_waitcnt vmcnt(0)" ::: "memory"); }
        // reads of buf[kt%3] must complete before kt+1 stages into it (kt+3%3)
        asm volatile("s_waitcnt lgkmcnt(0)" ::: "memory");
        __builtin_amdgcn_s_barrier();
        asm volatile("" ::: "memory");
    }

    // ---- epilogue: per-row (max, sum-exp, argmax) + in-tile diag ----
    // C/D layout: row = (lane>>4)*4 + reg, col = lane&15 (verified R1-R12).
    __syncthreads();
    float* sm = (float*)smem;              // [256][4] row max (logit units)
    float* sl = sm + 1024;                 // [256][4] sum exp
    int*   si = (int*)(sl + 1024);         // [256][4] argmax col
    float* sd = (float*)(si + 1024);       // [256] diag (logit units)
    const int g = lane >> 4;
#pragma unroll
    for (int mf = 0; mf < 4; ++mf) {
#pragma unroll
        for (int r = 0; r < 4; ++r) {
            const int row_loc  = wm * 64 + mf * 16 + g * 4 + r;
            const int row_glob = row0 + row_loc;
            const int ci = col0 + wn * 64 + (lane & 15);
            float vmax = acc[mf][0][r];
            int cbest = ci;
#pragma unroll
            for (int nf = 1; nf < 4; ++nf) {
                float v = acc[mf][nf][r];
                if (v > vmax) { vmax = v; cbest = ci + nf * 16; }
                if (ci + nf * 16 == row_glob) sd[row_loc] = v * TEMP_INV;
            }
            if (ci == row_glob) sd[row_loc] = acc[mf][0][r] * TEMP_INV;
#pragma unroll
            for (int m = 1; m < 16; m <<= 1) {
                float ov = __shfl_xor(vmax, m);
                int   oi = __shfl_xor(cbest, m);
                if (ov > vmax || (ov == vmax && oi < cbest)) { vmax = ov; cbest = oi; }
            }
            float ssum = 0.f;
#pragma unroll
            for (int nf = 0; nf < 4; ++nf)
                ssum += __expf((acc[mf][nf][r] - vmax) * TEMP_INV);
#pragma unroll
            for (int m = 1; m < 16; m <<= 1) ssum += __shfl_xor(ssum, m);
            if ((lane & 15) == 0) {
                sm[row_loc * 4 + wn] = vmax * TEMP_INV;
                sl[row_loc * 4 + wn] = ssum;
                si[row_loc * 4 + wn] = cbest;
            }
        }
    }
    __syncthreads();
    if (t < 256) {
        float M = sm[t * 4];
#pragma unroll
        for (int w = 1; w < 4; ++w) M = fmaxf(M, sm[t * 4 + w]);
        float L = 0.f;
#pragma unroll
        for (int w = 0; w < 4; ++w) L += sl[t * 4 + w] * __expf(sm[t * 4 + w] - M);
        float bv = -1e30f; int bi = 0;
#pragma unroll
        for (int w = 0; w < 4; ++w) {      // ascending wn: first-index tiebreak
            float v = sm[t * 4 + w];
            if (v > bv) { bv = v; bi = si[t * 4 + w]; }
        }
        part[(size_t)(row0 + t) * NCB + cb] =
            make_float4(M, L, __int_as_float(bi), sd[t]);
    }
}

// ---------------------------------------------------------------------------
// Kernel 3: per-row merge of 32 chunk partials -> loss_i / correct_i.
// One wave per row; lanes>=32 hold duplicates (zeroed for the sum).
// Diag comes from chunk (i>>8).
// ---------------------------------------------------------------------------
__global__ __launch_bounds__(256) void merge_kernel(
    const float4* __restrict__ part,
    float* __restrict__ loss_arr, float* __restrict__ corr_arr)
{
    int i    = blockIdx.x * 4 + (threadIdx.x >> 6);
    int lane = threadIdx.x & 63;
    float4 v = part[(size_t)i * NCB + (lane & 31)];

    float M = v.x;
#pragma unroll
    for (int off = 32; off; off >>= 1) M = fmaxf(M, __shfl_xor(M, off));
    float L = (lane < 32) ? v.y * __expf(v.x - M) : 0.f;
#pragma unroll
    for (int off = 32; off; off >>= 1) L += __shfl_xor(L, off);
    float bm = v.x; int bi = __float_as_int(v.z);
#pragma unroll
    for (int off = 1; off < 32; off <<= 1) {   // first-index tiebreak
        float ov = __shfl_xor(bm, off);
        int   oi = __shfl_xor(bi, off);
        if (ov > bm || (ov == bm && oi < bi)) { bm = ov; bi = oi; }
    }
    float dg = __shfl(v.w, i >> 8);
    if (lane == 0) {
        loss_arr[i] = (M + logf(L)) - dg;
        corr_arr[i] = (bi == i) ? 1.0f : 0.0f;
    }
}

// ---------------------------------------------------------------------------
// Kernel 4: deterministic single-block mean reduction -> d_out[0..1]
// ---------------------------------------------------------------------------
__global__ __launch_bounds__(256) void finalize_kernel(
    const float* __restrict__ loss_arr, const float* __restrict__ corr_arr,
    float* __restrict__ out, int n)
{
    float a = 0.f, b = 0.f;
    for (int i = threadIdx.x; i < n; i += 256) { a += loss_arr[i]; b += corr_arr[i]; }
#pragma unroll
    for (int off = 32; off; off >>= 1) { a += __shfl_xor(a, off); b += __shfl_xor(b, off); }
    __shared__ float sa[4], sb[4];
    int wid = threadIdx.x >> 6, lane = threadIdx.x & 63;
    if (lane == 0) { sa[wid] = a; sb[wid] = b; }
    __syncthreads();
    if (threadIdx.x == 0) {
        out[0] = (sa[0] + sa[1] + sa[2] + sa[3]) / n;
        out[1] = (sb[0] + sb[1] + sb[2] + sb[3]) / n;
    }
}

extern "C" void kernel_launch(void* const* d_in, const int* in_sizes, int n_in,
                              void* d_out, int out_size, void* d_ws, size_t ws_size,
                              hipStream_t stream)
{
    const float* x = (const float*)d_in[0];
    const float* q = (const float*)d_in[1];
    const int n = in_sizes[0] / CDIM;   // 8192

    char* ws = (char*)d_ws;
    size_t sz_bf = (size_t)n * CDIM * sizeof(u16);   // 8 MB each
    u16* xh = (u16*)(ws);
    u16* qh = (u16*)(ws + sz_bf);
    char* p = ws + 2 * sz_bf;
    float4* part = (float4*)p; p += (size_t)n * NCB * sizeof(float4);  // 4 MB
    float* loss_arr = (float*)p; p += (size_t)n * 4;
    float* corr_arr = (float*)p;

    norm_split_kernel<<<(2 * n) / 4, 256, 0, stream>>>(x, q, xh, qh, n);

    sim_main_kernel<<<(n / BM) * (n / BN), 1024, 3 * BUFSZ, stream>>>(xh, qh, part);

    merge_kernel<<<n / 4, 256, 0, stream>>>(part, loss_arr, corr_arr);

    finalize_kernel<<<1, 256, 0, stream>>>(loss_arr, corr_arr, (float*)d_out, n);
}

// Round 17
// 117.913 us; speedup vs baseline: 1.0405x; 1.0405x over previous
//
#include <hip/hip_runtime.h>
#include <hip/hip_bf16.h>
#include <math.h>

#define CDIM 512
#define NROW 8192
#define BM 256
#define BN 256
#define BK 32              // k elems per tile (32 B per row segment in fp8)
#define NT 16              // K tiles: 512/32
#define NCB 32             // column blocks (8192/256)
#define BUFSZ 16384        // A 8 KB + B 8 KB per K-tile buffer (fp8)
#define TEMP_INV 10.0f

typedef unsigned char  u8;
typedef unsigned short u16;
typedef float f32x4 __attribute__((ext_vector_type(4)));

static __device__ __forceinline__ void gload_lds16(const u8* g, char* l) {
    __builtin_amdgcn_global_load_lds(
        (const __attribute__((address_space(1))) void*)g,
        (__attribute__((address_space(3))) void*)l, 16, 0, 0);
}

// ---------------------------------------------------------------------------
// Kernel 1: row-normalize (fp32 math) -> fp8 e4m3 (HW cvt, OCP on gfx950).
// One wave per row; lane covers 8 consecutive elems -> uint2 (8 B) store.
// ---------------------------------------------------------------------------
__global__ __launch_bounds__(256) void norm_split_kernel(
    const float* __restrict__ x, const float* __restrict__ q,
    u8* __restrict__ xh, u8* __restrict__ qh, int n)
{
    int wave = blockIdx.x * 4 + (threadIdx.x >> 6);
    int lane = threadIdx.x & 63;
    const float* src; u8* dh; int row;
    if (wave < n) { src = x; dh = xh; row = wave; }
    else          { src = q; dh = qh; row = wave - n; }

    const float4* p = reinterpret_cast<const float4*>(src + (size_t)row * CDIM);
    float4 a = p[lane * 2];
    float4 b = p[lane * 2 + 1];
    float v[8] = {a.x, a.y, a.z, a.w, b.x, b.y, b.z, b.w};
    float ss = 0.f;
#pragma unroll
    for (int j = 0; j < 8; ++j) ss += v[j] * v[j];
#pragma unroll
    for (int off = 32; off; off >>= 1) ss += __shfl_xor(ss, off);
    float scale = 1.0f / fmaxf(sqrtf(ss), 1e-12f);

    unsigned r0 = __builtin_amdgcn_cvt_pk_fp8_f32(v[0] * scale, v[1] * scale, 0, 0);
    r0 = __builtin_amdgcn_cvt_pk_fp8_f32(v[2] * scale, v[3] * scale, r0, 1);
    unsigned r1 = __builtin_amdgcn_cvt_pk_fp8_f32(v[4] * scale, v[5] * scale, 0, 0);
    r1 = __builtin_amdgcn_cvt_pk_fp8_f32(v[6] * scale, v[7] * scale, r1, 1);
    uint2 o; o.x = r0; o.y = r1;
    *(uint2*)&dh[(size_t)row * CDIM + lane * 8] = o;
}

// ---------------------------------------------------------------------------
// Kernel 2 (R9 schedule, fp8 data): 256x256 tile, K=512, triple-buffered
// BK=32, one barrier per K-tile, 1024 threads = 16 waves (4x4), wave tile
// 64x64, mfma_f32_16x16x32_fp8_fp8 (i64 frags, 8B ds_read_b64).
// LDS rows are 32 B (two 16-B chunks). Conflict swizzle at 16-B granularity
// (keeps gload source 16B-aligned): phys_chunk = log_chunk ^ m01(row),
// m01(r) = ((r>>1)^(r>>2))&1 -> frag b64 reads <=2-way bank alias (free).
// Staging: waves 0-7 fill A (8 KB), waves 8-15 fill B; one gload_lds16 per
// wave per stage -> vmcnt(1) steady, vmcnt(0) at NT-2.
// XCD-resident blocking (R6/R9-verified). Fused epilogue unchanged.
// ---------------------------------------------------------------------------
__global__ __launch_bounds__(1024, 4) void sim_main_kernel(
    const u8* __restrict__ xh, const u8* __restrict__ qh,
    float4* __restrict__ part)
{
    extern __shared__ __align__(16) char smem[];   // 3 * 16384 = 48 KB
    const int t = threadIdx.x, lane = t & 63, wid = t >> 6;
    const int wm = wid >> 2, wn = wid & 3;

    // XCD-resident blocking: orig&7 = XCD (hw round-robin), rb outer, cb inner
    const int orig = blockIdx.x;
    const int xcd = orig & 7, s = orig >> 3;       // s in [0,128)
    const int rb = s >> 2;                          // 0..31
    const int cb = xcd * 4 + (s & 3);               // 0..31
    const int row0 = rb * BM, col0 = cb * BN;

    // ---- staging source (per-lane, pre-swizzled at 16B granularity) ----
    // waves 0-7: A region; waves 8-15: B region. tt = t&511 -> row tt>>1,
    // chunk tt&1; global chunk = chunk ^ m01(row).
    const int isB = wid >> 3;
    const int tt = t & 511;
    const int rr = tt >> 1, cch = tt & 1;
    const int m01s = ((rr >> 1) ^ (rr >> 2)) & 1;
    const u8* srow = isB ? (qh + (size_t)(col0 + rr) * CDIM)
                         : (xh + (size_t)(row0 + rr) * CDIM);
    const u8* sptr = srow + (cch ^ m01s) * 16;
    const unsigned dstw = (unsigned)(wid & 7) * 1024u + (unsigned)isB * 8192u;

    auto stage = [&](int kt) {
        gload_lds16(sptr + kt * BK, smem + (kt % 3) * BUFSZ + dstw);
    };

    // ---- frag read offsets (row stride 32 B, 4 slots of 8 B) ----
    // logical k-slot = lane>>4; phys slot = kslot ^ (m01(row)<<1), row=lane&15
    const int r4 = lane & 15;
    const unsigned slotx = ((unsigned)(lane >> 4)) ^ ((((r4 >> 1) ^ (r4 >> 2)) & 1) << 1);
    const unsigned aro = ((unsigned)(wm * 64 + r4)) * 32u + slotx * 8u;
    const unsigned bro = 8192u + ((unsigned)(wn * 64 + r4)) * 32u + slotx * 8u;

    f32x4 acc[4][4];
#pragma unroll
    for (int i = 0; i < 4; ++i)
#pragma unroll
        for (int j = 0; j < 4; ++j) acc[i][j] = (f32x4){0.f, 0.f, 0.f, 0.f};

    // prologue: lead-2
    stage(0); stage(1);
    asm volatile("s_waitcnt vmcnt(1)" ::: "memory");   // stage(0) landed
    __builtin_amdgcn_s_barrier();
    asm volatile("" ::: "memory");

    for (int kt = 0; kt < NT; ++kt) {
        const char* buf = smem + (kt % 3) * BUFSZ;
        // issue next-next stage FIRST (loads fly during reads+MFMA)
        if (kt < NT - 2) stage(kt + 2);
        long afr[4], bfr[4];
#pragma unroll
        for (int mf = 0; mf < 4; ++mf) afr[mf] = *(const long*)(buf + aro + mf * 512u);
#pragma unroll
        for (int nf = 0; nf < 4; ++nf) bfr[nf] = *(const long*)(buf + bro + nf * 512u);

        __builtin_amdgcn_s_setprio(1);
#pragma unroll
        for (int mf = 0; mf < 4; ++mf)
#pragma unroll
            for (int nf = 0; nf < 4; ++nf)
                acc[mf][nf] = __builtin_amdgcn_mfma_f32_16x16x32_fp8_fp8(
                    afr[mf], bfr[nf], acc[mf][nf], 0, 0, 0);
        __builtin_amdgcn_s_setprio(0);

        if (kt < NT - 2)       { asm volatile("s_waitcnt vmcnt(1)" ::: "memory"); }
        else if (kt == NT - 2) { asm volatile("s_waitcnt vmcnt(0)" ::: "memory"); }
        // reads of buf[kt%3] must complete before kt+1 stages into it (kt+3%3)
        asm volatile("s_waitcnt lgkmcnt(0)" ::: "memory");
        __builtin_amdgcn_s_barrier();
        asm volatile("" ::: "memory");
    }

    // ---- epilogue: per-row (max, sum-exp, argmax) + in-tile diag ----
    // C/D layout: row = (lane>>4)*4 + reg, col = lane&15 (shape-determined,
    // dtype-independent on gfx950 -- verified R1-R16 + guide m121-m128).
    __syncthreads();
    float* sm = (float*)smem;              // [256][4] row max (logit units)
    float* sl = sm + 1024;                 // [256][4] sum exp
    int*   si = (int*)(sl + 1024);         // [256][4] argmax col
    float* sd = (float*)(si + 1024);       // [256] diag (logit units)
    const int g = lane >> 4;
#pragma unroll
    for (int mf = 0; mf < 4; ++mf) {
#pragma unroll
        for (int r = 0; r < 4; ++r) {
            const int row_loc  = wm * 64 + mf * 16 + g * 4 + r;
            const int row_glob = row0 + row_loc;
            const int ci = col0 + wn * 64 + (lane & 15);
            float vmax = acc[mf][0][r];
            int cbest = ci;
#pragma unroll
            for (int nf = 1; nf < 4; ++nf) {
                float v = acc[mf][nf][r];
                if (v > vmax) { vmax = v; cbest = ci + nf * 16; }
                if (ci + nf * 16 == row_glob) sd[row_loc] = v * TEMP_INV;
            }
            if (ci == row_glob) sd[row_loc] = acc[mf][0][r] * TEMP_INV;
#pragma unroll
            for (int m = 1; m < 16; m <<= 1) {
                float ov = __shfl_xor(vmax, m);
                int   oi = __shfl_xor(cbest, m);
                if (ov > vmax || (ov == vmax && oi < cbest)) { vmax = ov; cbest = oi; }
            }
            float ssum = 0.f;
#pragma unroll
            for (int nf = 0; nf < 4; ++nf)
                ssum += __expf((acc[mf][nf][r] - vmax) * TEMP_INV);
#pragma unroll
            for (int m = 1; m < 16; m <<= 1) ssum += __shfl_xor(ssum, m);
            if ((lane & 15) == 0) {
                sm[row_loc * 4 + wn] = vmax * TEMP_INV;
                sl[row_loc * 4 + wn] = ssum;
                si[row_loc * 4 + wn] = cbest;
            }
        }
    }
    __syncthreads();
    if (t < 256) {
        float M = sm[t * 4];
#pragma unroll
        for (int w = 1; w < 4; ++w) M = fmaxf(M, sm[t * 4 + w]);
        float L = 0.f;
#pragma unroll
        for (int w = 0; w < 4; ++w) L += sl[t * 4 + w] * __expf(sm[t * 4 + w] - M);
        float bv = -1e30f; int bi = 0;
#pragma unroll
        for (int w = 0; w < 4; ++w) {      // ascending wn: first-index tiebreak
            float v = sm[t * 4 + w];
            if (v > bv) { bv = v; bi = si[t * 4 + w]; }
        }
        part[(size_t)(row0 + t) * NCB + cb] =
            make_float4(M, L, __int_as_float(bi), sd[t]);
    }
}

// ---------------------------------------------------------------------------
// Kernel 3: per-row merge of 32 chunk partials -> loss_i / correct_i.
// One wave per row; lanes>=32 hold duplicates (zeroed for the sum).
// Diag comes from chunk (i>>8).
// ---------------------------------------------------------------------------
__global__ __launch_bounds__(256) void merge_kernel(
    const float4* __restrict__ part,
    float* __restrict__ loss_arr, float* __restrict__ corr_arr)
{
    int i    = blockIdx.x * 4 + (threadIdx.x >> 6);
    int lane = threadIdx.x & 63;
    float4 v = part[(size_t)i * NCB + (lane & 31)];

    float M = v.x;
#pragma unroll
    for (int off = 32; off; off >>= 1) M = fmaxf(M, __shfl_xor(M, off));
    float L = (lane < 32) ? v.y * __expf(v.x - M) : 0.f;
#pragma unroll
    for (int off = 32; off; off >>= 1) L += __shfl_xor(L, off);
    float bm = v.x; int bi = __float_as_int(v.z);
#pragma unroll
    for (int off = 1; off < 32; off <<= 1) {   // first-index tiebreak
        float ov = __shfl_xor(bm, off);
        int   oi = __shfl_xor(bi, off);
        if (ov > bm || (ov == bm && oi < bi)) { bm = ov; bi = oi; }
    }
    float dg = __shfl(v.w, i >> 8);
    if (lane == 0) {
        loss_arr[i] = (M + logf(L)) - dg;
        corr_arr[i] = (bi == i) ? 1.0f : 0.0f;
    }
}

// ---------------------------------------------------------------------------
// Kernel 4: deterministic single-block mean reduction -> d_out[0..1]
// ---------------------------------------------------------------------------
__global__ __launch_bounds__(256) void finalize_kernel(
    const float* __restrict__ loss_arr, const float* __restrict__ corr_arr,
    float* __restrict__ out, int n)
{
    float a = 0.f, b = 0.f;
    for (int i = threadIdx.x; i < n; i += 256) { a += loss_arr[i]; b += corr_arr[i]; }
#pragma unroll
    for (int off = 32; off; off >>= 1) { a += __shfl_xor(a, off); b += __shfl_xor(b, off); }
    __shared__ float sa[4], sb[4];
    int wid = threadIdx.x >> 6, lane = threadIdx.x & 63;
    if (lane == 0) { sa[wid] = a; sb[wid] = b; }
    __syncthreads();
    if (threadIdx.x == 0) {
        out[0] = (sa[0] + sa[1] + sa[2] + sa[3]) / n;
        out[1] = (sb[0] + sb[1] + sb[2] + sb[3]) / n;
    }
}

extern "C" void kernel_launch(void* const* d_in, const int* in_sizes, int n_in,
                              void* d_out, int out_size, void* d_ws, size_t ws_size,
                              hipStream_t stream)
{
    const float* x = (const float*)d_in[0];
    const float* q = (const float*)d_in[1];
    const int n = in_sizes[0] / CDIM;   // 8192

    char* ws = (char*)d_ws;
    size_t sz_f8 = (size_t)n * CDIM;                 // 4 MB each
    u8* xh = (u8*)(ws);
    u8* qh = (u8*)(ws + sz_f8);
    char* p = ws + 2 * sz_f8;
    float4* part = (float4*)p; p += (size_t)n * NCB * sizeof(float4);  // 4 MB
    float* loss_arr = (float*)p; p += (size_t)n * 4;
    float* corr_arr = (float*)p;

    norm_split_kernel<<<(2 * n) / 4, 256, 0, stream>>>(x, q, xh, qh, n);

    sim_main_kernel<<<(n / BM) * (n / BN), 1024, 3 * BUFSZ, stream>>>(xh, qh, part);

    merge_kernel<<<n / 4, 256, 0, stream>>>(part, loss_arr, corr_arr);

    finalize_kernel<<<1, 256, 0, stream>>>(loss_arr, corr_arr, (float*)d_out, n);
}